// Round 1
// baseline (626.843 us; speedup 1.0000x reference)
//
#include <hip/hip_runtime.h>

// Problem constants
#define BATCH 4
#define TOK   2304
#define CH    512
#define NHEAD 8
#define HDIM  64
#define F3    1536            // 3*CH

// y[b] flat layout: [2304, 1536]; Q/K/V are contiguous thirds viewed [2304, 512]
#define YB_STRIDE ((long)TOK * F3)       // 3,538,944 floats per batch
#define QKV_SZ    ((long)TOK * CH)       // 1,179,648 floats per third

// ---------------------------------------------------------------------------
// GEMM NT: C[M,N] = A[M,K] @ B[N,K]^T + bias[N]
// A row-major (lda=K), B row-major (ldb=K), C row-major (ldc=N).
// Batched over blockIdx.z with element strides sA/sB/sC.
// Tile 128x128, K-step 16, 256 threads, 8x8 micro-tile.
// ---------------------------------------------------------------------------
__global__ __launch_bounds__(256) void gemm_nt128(
    const float* __restrict__ A, const float* __restrict__ B,
    const float* __restrict__ bias, float* __restrict__ C,
    int M, int N, int K, long sA, long sB, long sC)
{
    A += (long)blockIdx.z * sA;
    B += (long)blockIdx.z * sB;
    C += (long)blockIdx.z * sC;

    __shared__ float As[128][17];   // pad 17: B-side reads land 4-way max
    __shared__ float Bs[128][17];

    const int tid  = threadIdx.x;
    const int tx   = tid & 15;      // col group 0..15
    const int ty   = tid >> 4;      // row group 0..15
    const int row0 = blockIdx.y * 128;
    const int col0 = blockIdx.x * 128;

    float acc[8][8] = {};

    for (int k0 = 0; k0 < K; k0 += 16) {
        // stage A,B tiles: 128x16 floats each = 512 float4 per tile, 2/thread
        #pragma unroll
        for (int t = 0; t < 2; ++t) {
            const int idx = tid + t * 256;        // 0..511
            const int r   = idx >> 2;
            const int k4  = (idx & 3) << 2;
            const float4 av = *(const float4*)&A[(long)(row0 + r) * K + k0 + k4];
            const float4 bv = *(const float4*)&B[(long)(col0 + r) * K + k0 + k4];
            As[r][k4+0] = av.x; As[r][k4+1] = av.y; As[r][k4+2] = av.z; As[r][k4+3] = av.w;
            Bs[r][k4+0] = bv.x; Bs[r][k4+1] = bv.y; Bs[r][k4+2] = bv.z; Bs[r][k4+3] = bv.w;
        }
        __syncthreads();

        #pragma unroll
        for (int kk = 0; kk < 16; ++kk) {
            float a[8], b[8];
            #pragma unroll
            for (int i = 0; i < 8; ++i) a[i] = As[ty*8 + i][kk];
            #pragma unroll
            for (int j = 0; j < 8; ++j) b[j] = Bs[tx*8 + j][kk];
            #pragma unroll
            for (int i = 0; i < 8; ++i)
                #pragma unroll
                for (int j = 0; j < 8; ++j)
                    acc[i][j] = fmaf(a[i], b[j], acc[i][j]);
        }
        __syncthreads();
    }

    #pragma unroll
    for (int i = 0; i < 8; ++i) {
        const long r = row0 + ty*8 + i;
        #pragma unroll
        for (int j = 0; j < 8; ++j) {
            const int c = col0 + tx*8 + j;
            C[r * N + c] = acc[i][j] + bias[c];
        }
    }
}

// ---------------------------------------------------------------------------
// K2a: Mt[b,h][d][d'] = (1/8) * sum_n K[b,h][n,d'] * V[b,h][n,d]
// (stored TRANSPOSED so K2b reads are coalesced).
// One block per (b,h), 1024 threads, 2x2 micro-tile, n staged 64 at a time.
// ---------------------------------------------------------------------------
__global__ __launch_bounds__(1024) void ktv_kernel(
    const float* __restrict__ y, float* __restrict__ Mt)
{
    const int bh = blockIdx.x;              // 0..31
    const int b  = bh >> 3, h = bh & 7;
    const float* Kp = y + (long)b * YB_STRIDE + 1 * QKV_SZ + h * HDIM;
    const float* Vp = y + (long)b * YB_STRIDE + 2 * QKV_SZ + h * HDIM;

    __shared__ float Ks[64][68];
    __shared__ float Vs[64][68];

    const int tid = threadIdx.x;
    const int tx  = tid & 31;               // d  group
    const int ty  = tid >> 5;               // d' group 0..31
    const int lr  = tid >> 4;               // loader row 0..63
    const int lc4 = (tid & 15) << 2;        // loader col*4

    float acc[2][2] = {};                   // [i -> d'][j -> d]

    for (int n0 = 0; n0 < TOK; n0 += 64) {
        const float4 kv = *(const float4*)&Kp[(long)(n0 + lr) * CH + lc4];
        const float4 vv = *(const float4*)&Vp[(long)(n0 + lr) * CH + lc4];
        Ks[lr][lc4+0] = kv.x; Ks[lr][lc4+1] = kv.y; Ks[lr][lc4+2] = kv.z; Ks[lr][lc4+3] = kv.w;
        Vs[lr][lc4+0] = vv.x; Vs[lr][lc4+1] = vv.y; Vs[lr][lc4+2] = vv.z; Vs[lr][lc4+3] = vv.w;
        __syncthreads();
        #pragma unroll 16
        for (int nn = 0; nn < 64; ++nn) {
            const float a0 = Ks[nn][ty*2+0], a1 = Ks[nn][ty*2+1];
            const float b0 = Vs[nn][tx*2+0], b1 = Vs[nn][tx*2+1];
            acc[0][0] = fmaf(a0, b0, acc[0][0]);
            acc[0][1] = fmaf(a0, b1, acc[0][1]);
            acc[1][0] = fmaf(a1, b0, acc[1][0]);
            acc[1][1] = fmaf(a1, b1, acc[1][1]);
        }
        __syncthreads();
    }

    float* Mo = Mt + (long)bh * (HDIM * HDIM);
    #pragma unroll
    for (int i = 0; i < 2; ++i)
        #pragma unroll
        for (int j = 0; j < 2; ++j)
            Mo[(tx*2 + j) * HDIM + (ty*2 + i)] = acc[i][j] * 0.125f;  // Mt[d][d']
}

// ---------------------------------------------------------------------------
// K2b: PcatT[b][f][c=64h+d'] = sum_d Mt[b,h][d][d'] * w_out[f, 64h+d]
// One thread per output element; Mt reads coalesced (d' fastest), w_out broadcast.
// ---------------------------------------------------------------------------
__global__ __launch_bounds__(256) void pmat_kernel(
    const float* __restrict__ Mt, const float* __restrict__ w_out,
    float* __restrict__ Pt)
{
    const int idx = blockIdx.x * 256 + threadIdx.x;   // 0 .. 4*512*512-1
    const int b   = idx >> 18;
    const int f   = (idx >> 9) & 511;
    const int c   = idx & 511;
    const int h   = c >> 6;
    const int dp  = c & 63;
    const float* Mo = Mt + ((long)(b * NHEAD + h)) * (HDIM * HDIM);
    const float* wr = w_out + (long)f * CH + h * HDIM;
    float acc = 0.f;
    #pragma unroll 16
    for (int d = 0; d < HDIM; ++d)
        acc = fmaf(Mo[d * HDIM + dp], wr[d], acc);
    Pt[idx] = acc;
}

// ---------------------------------------------------------------------------
extern "C" void kernel_launch(void* const* d_in, const int* in_sizes, int n_in,
                              void* d_out, int out_size, void* d_ws, size_t ws_size,
                              hipStream_t stream)
{
    const float* x     = (const float*)d_in[0];   // [4,2304,512]
    const float* w_in  = (const float*)d_in[1];   // [1536,512]
    const float* b_in  = (const float*)d_in[2];   // [1536]
    const float* w_out = (const float*)d_in[3];   // [512,512]
    const float* b_out = (const float*)d_in[4];   // [512]
    float* out = (float*)d_out;                   // [4,2304,512]

    float* ws = (float*)d_ws;
    float* y  = ws;                                        // 14,155,776 f
    float* Mt = ws + BATCH * YB_STRIDE;                    //    131,072 f
    float* Pt = Mt + (long)BATCH * NHEAD * HDIM * HDIM;    //  1,048,576 f

    // K1: y = x @ w_in^T + b_in   [9216,512]x[512,1536]
    {
        dim3 grid(F3 / 128, (BATCH * TOK) / 128, 1);
        gemm_nt128<<<grid, 256, 0, stream>>>(x, w_in, b_in, y,
                                             BATCH * TOK, F3, CH, 0, 0, 0);
    }
    // K2a: Mt[b,h] = (K^T V)/8 (transposed)
    ktv_kernel<<<dim3(BATCH * NHEAD), 1024, 0, stream>>>(y, Mt);

    // K2b: PcatT[b] = fold(M, w_out)
    pmat_kernel<<<dim3((BATCH * CH * CH) / 256), 256, 0, stream>>>(Mt, w_out, Pt);

    // K3: out[b] = Q[b] @ PcatT[b]^T + b_out   per batch [2304,512]x[512,512]
    {
        dim3 grid(CH / 128, TOK / 128, BATCH);
        gemm_nt128<<<grid, 256, 0, stream>>>(y, Pt, b_out, out,
                                             TOK, CH, CH,
                                             YB_STRIDE, (long)CH * CH, (long)TOK * CH);
    }
}

// Round 3
// 87.683 us; speedup vs baseline: 7.1490x; 7.1490x over previous
//
#include <hip/hip_runtime.h>
#include <hip/hip_bf16.h>

#define BATCH 4
#define TOK   2304
#define CH    512
#define NHEAD 8
#define HDIM  64
#define F3    1536
#define YB_STRIDE ((long)TOK * F3)   // y per-batch stride (elements)
#define QKV_SZ    ((long)TOK * CH)   // one Q/K/V third (elements)
#define KVCHUNK   18                 // token chunks for K^T V partials (2304/18=128)

typedef __attribute__((ext_vector_type(8))) short short8;   // 8 bf16 = 4 VGPRs
typedef __attribute__((ext_vector_type(4))) float f32x4;

__device__ inline ushort f2b(float f) {
    __hip_bfloat16 h = __float2bfloat16(f);
    return *reinterpret_cast<ushort*>(&h);
}
__device__ inline void unp(unsigned int u, float& lo, float& hi) {
    union { unsigned int i; float f; } a, c;
    a.i = u << 16; c.i = u & 0xffff0000u;
    lo = a.f; hi = c.f;
}

// global -> LDS direct copy, 16B per lane; lds dest = wave-uniform base + lane*16
#define GLL(gp, lp) __builtin_amdgcn_global_load_lds( \
    (const __attribute__((address_space(1))) unsigned int*)(gp), \
    (__attribute__((address_space(3))) unsigned int*)(lp), 16, 0, 0)

// ---------------------------------------------------------------------------
// K0: fp32 -> bf16 convert (RNE), 4 elems/thread
// ---------------------------------------------------------------------------
__global__ __launch_bounds__(256) void cvt_bf16(const float* __restrict__ in,
                                                ushort* __restrict__ out, int n4) {
    const int i = blockIdx.x * 256 + threadIdx.x;
    if (i >= n4) return;
    const float4 v = ((const float4*)in)[i];
    ushort4 o;
    o.x = f2b(v.x); o.y = f2b(v.y); o.z = f2b(v.z); o.w = f2b(v.w);
    ((ushort4*)out)[i] = o;
}

// ---------------------------------------------------------------------------
// MFMA GEMM NT: C[M,N] = A[M,K] @ B[N,K]^T + bias[N]
// A,B bf16 row-major (ld=K); C fp32 or bf16 row-major (ld=N).
// 128x128 tile, BK=32, 256 threads (4 waves, each a 64x64 quadrant),
// global_load_lds width-16 staging, 16x16x32 bf16 MFMA, fp32 accum.
// NT with identical A/B fragment load patterns: per-lane k-slot permutation
// cancels between operands; only the C/D mapping must be exact (m89).
// ---------------------------------------------------------------------------
template<bool OUT_BF16>
__global__ __launch_bounds__(256) void mfma_gemm_nt(
    const ushort* __restrict__ A, const ushort* __restrict__ B,
    const float* __restrict__ bias, void* __restrict__ Cout,
    int M, int N, int K, long sA, long sB, long sC)
{
    A += (long)blockIdx.z * sA;
    B += (long)blockIdx.z * sB;

    __shared__ __align__(16) ushort As[128 * 32];   // 8 KB, row-major [128][32]
    __shared__ __align__(16) ushort Bs[128 * 32];

    const int tid  = threadIdx.x;
    const int lane = tid & 63;
    const int wave = tid >> 6;            // 0..3
    const int wr   = (wave >> 1) * 64;    // wave row quadrant
    const int wc   = (wave & 1) * 64;     // wave col quadrant
    const int row0 = blockIdx.y * 128;
    const int col0 = blockIdx.x * 128;

    // staging: thread t fetches 16B destined for LDS byte t*16 (+4096 for 2nd inst)
    const int sr = tid >> 2;              // row 0..63
    const int sc = (tid & 3) * 8;         // bf16 col offset
    const ushort* gA0 = A + (long)(row0 + sr) * K + sc;
    const ushort* gA1 = A + (long)(row0 + sr + 64) * K + sc;
    const ushort* gB0 = B + (long)(col0 + sr) * K + sc;
    const ushort* gB1 = B + (long)(col0 + sr + 64) * K + sc;

    char* lA = (char*)As + wave * 1024;   // wave-uniform LDS dest
    char* lB = (char*)Bs + wave * 1024;

    const int fr = lane & 15;             // fragment row/col
    const int kg = (lane >> 4) * 8;       // fragment k offset

    f32x4 acc[4][4] = {};

    for (int k0 = 0; k0 < K; k0 += 32) {
        if (k0) __syncthreads();          // prev compute done before overwrite
        GLL(gA0 + k0, lA);
        GLL(gA1 + k0, lA + 4096);
        GLL(gB0 + k0, lB);
        GLL(gB1 + k0, lB + 4096);
        __syncthreads();                  // drains vmcnt -> tiles ready

        short8 a[4], b[4];
        #pragma unroll
        for (int m = 0; m < 4; ++m)
            a[m] = *(const short8*)(As + (wr + m * 16 + fr) * 32 + kg);
        #pragma unroll
        for (int n = 0; n < 4; ++n)
            b[n] = *(const short8*)(Bs + (wc + n * 16 + fr) * 32 + kg);

        #pragma unroll
        for (int m = 0; m < 4; ++m)
            #pragma unroll
            for (int n = 0; n < 4; ++n)
                acc[m][n] = __builtin_amdgcn_mfma_f32_16x16x32_bf16(
                    a[m], b[n], acc[m][n], 0, 0, 0);
    }

    // epilogue: D row = (lane>>4)*4 + reg, col = lane&15  (m89-verified)
    const int rbase = row0 + wr + (lane >> 4) * 4;
    const int cbase = col0 + wc + (lane & 15);
    const long zoff = (long)blockIdx.z * sC;
    #pragma unroll
    for (int m = 0; m < 4; ++m) {
        #pragma unroll
        for (int n = 0; n < 4; ++n) {
            const int c = cbase + n * 16;
            const float bv = bias[c];
            #pragma unroll
            for (int r = 0; r < 4; ++r) {
                const long off = zoff + (long)(rbase + m * 16 + r) * N + c;
                const float v = acc[m][n][r] + bv;
                if (OUT_BF16) ((ushort*)Cout)[off] = f2b(v);
                else          ((float*)Cout)[off]  = v;
            }
        }
    }
}

// ---------------------------------------------------------------------------
// K2a: partial sums over a 128-token chunk, stored TRANSPOSED (V-dim first):
//   Mtp[chunk][bh][dp][d] = (1/8) * sum_{n in chunk} V[n][dp] * K[n][d]
// so K2b can contract the FIRST index (V-dim) with w_out (round-1 semantics).
// Grid (KVCHUNK, 32). bf16 in, fp32 LDS, 4x4 micro-tile.
// ---------------------------------------------------------------------------
__global__ __launch_bounds__(256) void ktv_partial(
    const ushort* __restrict__ y, float* __restrict__ Mtp)
{
    const int chunk = blockIdx.x;          // 0..17 (128 tokens each)
    const int bh    = blockIdx.y;          // 0..31
    const int b = bh >> 3, h = bh & 7;
    const ushort* Kp = y + (long)b * YB_STRIDE + QKV_SZ     + h * HDIM;
    const ushort* Vp = y + (long)b * YB_STRIDE + 2 * QKV_SZ + h * HDIM;

    __shared__ __align__(16) float Ks[64][68];
    __shared__ __align__(16) float Vs[64][68];

    const int tid = threadIdx.x;
    const int tx = tid & 15, ty = tid >> 4;
    const int lr = tid >> 2;               // stage row 0..63
    const int ls = (tid & 3) * 16;         // stage col (16 bf16 per thread)

    float acc[4][4] = {};                  // acc[i -> d (K-dim)][j -> dp (V-dim)]

    for (int s = 0; s < 2; ++s) {
        const int n0 = chunk * 128 + s * 64;
        const ushort* kr = Kp + (long)(n0 + lr) * CH + ls;
        const ushort* vr = Vp + (long)(n0 + lr) * CH + ls;
        const uint4 k0 = *(const uint4*)kr;
        const uint4 k1 = *(const uint4*)(kr + 8);
        const uint4 v0 = *(const uint4*)vr;
        const uint4 v1 = *(const uint4*)(vr + 8);
        if (s) __syncthreads();
        unsigned int kw[8] = {k0.x,k0.y,k0.z,k0.w,k1.x,k1.y,k1.z,k1.w};
        unsigned int vw[8] = {v0.x,v0.y,v0.z,v0.w,v1.x,v1.y,v1.z,v1.w};
        #pragma unroll
        for (int t = 0; t < 8; ++t) {
            unp(kw[t], Ks[lr][ls + 2*t], Ks[lr][ls + 2*t + 1]);
            unp(vw[t], Vs[lr][ls + 2*t], Vs[lr][ls + 2*t + 1]);
        }
        __syncthreads();

        #pragma unroll 8
        for (int nn = 0; nn < 64; ++nn) {
            const float4 ka = *(const float4*)&Ks[nn][ty * 4];
            const float4 vb = *(const float4*)&Vs[nn][tx * 4];
            const float kk[4] = {ka.x, ka.y, ka.z, ka.w};
            const float vv[4] = {vb.x, vb.y, vb.z, vb.w};
            #pragma unroll
            for (int i = 0; i < 4; ++i)
                #pragma unroll
                for (int j = 0; j < 4; ++j)
                    acc[i][j] = fmaf(kk[i], vv[j], acc[i][j]);
        }
    }

    // TRANSPOSED store: Mo[dp][d] with dp = tx*4+j (V-dim), d = ty*4+i (K-dim)
    float* Mo = Mtp + ((long)chunk * 32 + bh) * 4096;
    #pragma unroll
    for (int j = 0; j < 4; ++j) {
        float4 st;
        st.x = acc[0][j] * 0.125f; st.y = acc[1][j] * 0.125f;
        st.z = acc[2][j] * 0.125f; st.w = acc[3][j] * 0.125f;
        *(float4*)&Mo[(tx * 4 + j) * 64 + ty * 4] = st;
    }
}

// ---------------------------------------------------------------------------
// K2b: Pt[b][f][64h+q] = sum_e w_out[f][64h+e] * M[q][e]
// with Ms[e][q] = sum_n V[n][e]*K[n][q] (V-dim first, from K2a).
// Grid (8 f-blocks, 32 bh). Output bf16 for K3's B operand.
// ---------------------------------------------------------------------------
__global__ __launch_bounds__(256) void fold_pt(
    const float* __restrict__ Mtp, const float* __restrict__ w_out,
    ushort* __restrict__ Pt)
{
    const int fc = blockIdx.x;   // 0..7
    const int bh = blockIdx.y;   // 0..31
    const int b = bh >> 3, h = bh & 7;

    __shared__ __align__(16) float Ms[64][68];

    const int tid = threadIdx.x;
    const int tx = tid & 15, ty = tid >> 4;

    #pragma unroll
    for (int j = 0; j < 16; ++j) {
        const int e = j * 256 + tid;       // 0..4095
        float sum = 0.f;
        #pragma unroll
        for (int c = 0; c < KVCHUNK; ++c)
            sum += Mtp[((long)c * 32 + bh) * 4096 + e];
        Ms[e >> 6][e & 63] = sum;
    }
    __syncthreads();

    const int fbase = fc * 64 + ty * 4;
    float acc[4][4] = {};
    for (int d = 0; d < 64; ++d) {
        const float4 mv = *(const float4*)&Ms[d][tx * 4];
        const float mm[4] = {mv.x, mv.y, mv.z, mv.w};
        #pragma unroll
        for (int i = 0; i < 4; ++i) {
            const float w = w_out[(long)(fbase + i) * CH + h * HDIM + d];
            #pragma unroll
            for (int j = 0; j < 4; ++j)
                acc[i][j] = fmaf(w, mm[j], acc[i][j]);
        }
    }
    #pragma unroll
    for (int i = 0; i < 4; ++i) {
        ushort4 o;
        o.x = f2b(acc[i][0]); o.y = f2b(acc[i][1]);
        o.z = f2b(acc[i][2]); o.w = f2b(acc[i][3]);
        *(ushort4*)&Pt[(((long)b * CH) + fbase + i) * CH + h * HDIM + tx * 4] = o;
    }
}

// ---------------------------------------------------------------------------
extern "C" void kernel_launch(void* const* d_in, const int* in_sizes, int n_in,
                              void* d_out, int out_size, void* d_ws, size_t ws_size,
                              hipStream_t stream)
{
    const float* x     = (const float*)d_in[0];   // [4,2304,512]
    const float* w_in  = (const float*)d_in[1];   // [1536,512]
    const float* b_in  = (const float*)d_in[2];   // [1536]
    const float* w_out = (const float*)d_in[3];   // [512,512]
    const float* b_out = (const float*)d_in[4];   // [512]
    float* out = (float*)d_out;                   // [4,2304,512] fp32

    char* ws = (char*)d_ws;
    ushort* xb  = (ushort*)ws;                       //  9,437,184 B
    ushort* wb  = (ushort*)(ws + 9437184);           //  1,572,864 B
    ushort* y   = (ushort*)(ws + 11010048);          // 28,311,552 B (bf16 [4][2304][1536])
    float*  Mtp = (float*) (ws + 39321600);          //  9,437,184 B (18 chunk partials)
    ushort* Pt  = (ushort*)(ws + 48758784);          //  2,097,152 B -> total 50.9 MB

    // K0: converts
    cvt_bf16<<<4608, 256, 0, stream>>>(x, xb, 1179648);
    cvt_bf16<<<768, 256, 0, stream>>>(w_in, wb, 196608);

    // K1: y = x @ w_in^T + b_in  (bf16 out)  M=9216 N=1536 K=512
    mfma_gemm_nt<true><<<dim3(F3 / 128, (BATCH * TOK) / 128, 1), 256, 0, stream>>>(
        xb, wb, b_in, y, BATCH * TOK, F3, CH, 0, 0, 0);

    // K2a: chunk-partial V^T-major (K^T V)/8
    ktv_partial<<<dim3(KVCHUNK, BATCH * NHEAD), 256, 0, stream>>>(y, Mtp);

    // K2b: reduce chunks + fold w_out -> Pt bf16
    fold_pt<<<dim3(8, BATCH * NHEAD), 256, 0, stream>>>(Mtp, w_out, Pt);

    // K3: out[b] = Q[b] @ Pt[b]^T + b_out  (fp32 out)  M=2304 N=512 K=512, z=4
    mfma_gemm_nt<false><<<dim3(CH / 128, TOK / 128, BATCH), 256, 0, stream>>>(
        y, Pt, b_out, out, TOK, CH, CH, YB_STRIDE, (long)CH * CH, QKV_SZ);
}

// Round 5
// 77.939 us; speedup vs baseline: 8.0428x; 1.1250x over previous
//
#include <hip/hip_runtime.h>
#include <hip/hip_bf16.h>

#define BATCH 4
#define TOK   2304
#define CH    512
#define NHEAD 8
#define HDIM  64
#define F3    1536
#define YB_STRIDE ((long)TOK * F3)   // y per-batch stride (elements)
#define QKV_SZ    ((long)TOK * CH)   // one Q/K/V third (elements)
#define KVCHUNK   18                 // token chunks for K^T V partials (2304/18=128)

typedef __attribute__((ext_vector_type(8))) short short8;   // 8 bf16 = 4 VGPRs
typedef __attribute__((ext_vector_type(4))) float f32x4;

__device__ inline ushort f2b(float f) {
    __hip_bfloat16 h = __float2bfloat16(f);
    return *reinterpret_cast<ushort*>(&h);
}
__device__ inline void unp(unsigned int u, float& lo, float& hi) {
    union { unsigned int i; float f; } a, c;
    a.i = u << 16; c.i = u & 0xffff0000u;
    lo = a.f; hi = c.f;
}

// global -> LDS direct copy, 16B per lane; lds dest = wave-uniform base + lane*16
#define GLL(gp, lp) __builtin_amdgcn_global_load_lds( \
    (const __attribute__((address_space(1))) unsigned int*)(gp), \
    (__attribute__((address_space(3))) unsigned int*)(lp), 16, 0, 0)

// ---------------------------------------------------------------------------
// K0: fp32 -> bf16 convert for x and w_in in one launch (wb contiguous after xb)
// ---------------------------------------------------------------------------
__global__ __launch_bounds__(256) void cvt_bf16_2(
    const float* __restrict__ x, const float* __restrict__ w,
    ushort* __restrict__ xb_wb, int nx4, int nw4)
{
    const int i = blockIdx.x * 256 + threadIdx.x;
    float4 v;
    if (i < nx4)                v = ((const float4*)x)[i];
    else if (i < nx4 + nw4)     v = ((const float4*)w)[i - nx4];
    else return;
    ushort4 o;
    o.x = f2b(v.x); o.y = f2b(v.y); o.z = f2b(v.z); o.w = f2b(v.w);
    ((ushort4*)xb_wb)[i] = o;
}

// ---------------------------------------------------------------------------
// K1: 256x256-tile, BK=64, 8-wave (2Mx4N), 8-phase counted-vmcnt MFMA GEMM NT.
//   C[M,N] = A[M,K] @ B[N,K]^T + bias[N]
// LDS 128KB: A dbuf [2][256][64] @0, B dbuf [2][256][64] @64KB.
// st-swizzle: phys_col_byte = nom ^ ((row&7)<<4), applied on GLL SOURCE (inverse)
// and ds_read ADDR (forward) -> data nominal, banks spread (rule 21 / T2).
//
// READ-SEAL constraints (r4 bug-fix): current-buf regions' last ds_read:
//   A-lo,A-hi @P2 (LDA8(t,0)@P1, LDA8(t,1)@P2)  -> stage at P3+
//   B-lo,B-hi @P3 (LDB8(t,0)@P1, LDB8(t,1)@P3)  -> stage at P4 only
// Staging stream per tile t: P1:Bhi(t+1)[other buf, always safe]
//                            P3:Alo(t+2)  P4:Ahi(t+2),Blo(t+2).
// Ledger: end-of-t VMC(6) leaves exactly {Alo,Ahi,Blo}(t+2) in flight (6 ops),
// retires Bhi(t+1) -> tile t+1 fully landed. t=NT-2: VMC(0). t=NT-1: none.
// Prologue: tile0 (8 ops) + {Blo,Alo,Ahi}(1) (6 ops); VMC(6) retires tile0.
// ---------------------------------------------------------------------------
template<int KDIM, bool OUT_BF16>
__global__ __launch_bounds__(512, 2) void gemm256_8ph(
    const ushort* __restrict__ A, const ushort* __restrict__ B,
    const float* __restrict__ bias, void* __restrict__ Cout, int N)
{
    constexpr int NT = KDIM / 64;
    __shared__ __align__(16) char smem[131072];

    const int tid  = threadIdx.x;
    const int lane = tid & 63, wave = tid >> 6;
    const int wm = wave >> 2, wn = wave & 3;           // 2 x 4 wave grid
    const int row0 = blockIdx.y * 256, col0 = blockIdx.x * 256;

    // staging invariants: thread covers LDS linear (srow, (tid&7)*16B) per chunk
    const int srow = tid >> 3;                          // 0..63 within chunk
    const int scol = ((tid & 7) ^ (srow & 7)) << 3;     // inverse-swizzled src col (elems)
    const ushort* gA = A + (long)(row0 + srow) * KDIM + scol;
    const ushort* gB = B + (long)(col0 + srow) * KDIM + scol;
    char* ldsW = smem + wave * 1024;                    // + op*65536 + buf*32768 + half*16384 + chunk*8192

    // fragment-read invariants
    const int l15 = lane & 15, lg = lane >> 4, l7 = lane & 7;
    const int cp[2] = { (lg * 16) ^ (l7 * 16), (64 + lg * 16) ^ (l7 * 16) };
    const char* rdA = smem + (wm * 128 + l15) * 128;
    const char* rdB = smem + 65536 + (wn * 64 + l15) * 128;

    f32x4  acc[8][4] = {};
    short8 a[2][4][2], b[2][2];

#define STAGE8(op, t, h) do { \
    const ushort* _g = ((op) ? gB : gA) + ((h) * 128) * KDIM + (t) * 64; \
    char* _l = ldsW + (op) * 65536 + ((t) & 1) * 32768 + (h) * 16384; \
    GLL(_g, _l); \
    GLL(_g + 64 * KDIM, _l + 8192); \
} while (0)

#define LDA8(t, mh) do { \
    const char* _p = rdA + ((t) & 1) * 32768 + (mh) * 8192; \
    _Pragma("unroll") for (int mf = 0; mf < 4; ++mf) { \
        a[mh][mf][0] = *(const short8*)(_p + mf * 2048 + cp[0]); \
        a[mh][mf][1] = *(const short8*)(_p + mf * 2048 + cp[1]); } \
} while (0)

#define LDB8(t, nh) do { \
    const char* _p = rdB + ((t) & 1) * 32768 + (nh) * 4096; \
    _Pragma("unroll") for (int j = 0; j < 2; ++j) { \
        b[j][0] = *(const short8*)(_p + j * 2048 + cp[0]); \
        b[j][1] = *(const short8*)(_p + j * 2048 + cp[1]); } \
} while (0)

#define MFMAQ(mh, nh) do { \
    _Pragma("unroll") for (int mf = 0; mf < 4; ++mf) \
    _Pragma("unroll") for (int j = 0; j < 2; ++j) \
    _Pragma("unroll") for (int ks = 0; ks < 2; ++ks) \
        acc[(mh)*4+mf][(nh)*2+j] = __builtin_amdgcn_mfma_f32_16x16x32_bf16( \
            a[mh][mf][ks], b[j][ks], acc[(mh)*4+mf][(nh)*2+j], 0, 0, 0); \
} while (0)

#define BAR8() __builtin_amdgcn_s_barrier()
#define VMC(n) asm volatile("s_waitcnt vmcnt(" #n ")" ::: "memory")

    // ---- prologue: tile0 (4 half-tiles) + tile1 {Blo, Alo, Ahi}
    STAGE8(0, 0, 0); STAGE8(0, 0, 1); STAGE8(1, 0, 0); STAGE8(1, 0, 1);
    VMC(4);
    STAGE8(1, 1, 0); STAGE8(0, 1, 0); STAGE8(0, 1, 1);
    VMC(6);                               // 14 issued, retire oldest 8 = all tile0
    BAR8();

#pragma unroll
    for (int t = 0; t < NT; ++t) {
        // P1: quadrant (0,0)
        LDA8(t, 0); LDB8(t, 0);
        if (t + 1 < NT) STAGE8(1, t + 1, 1);          // Bhi(t+1) -> other buf (always safe)
        BAR8(); __builtin_amdgcn_s_setprio(1); MFMAQ(0, 0); __builtin_amdgcn_s_setprio(0); BAR8();
        // P2: quadrant (1,0) — no staging (no region is sealed yet)
        LDA8(t, 1);
        BAR8(); __builtin_amdgcn_s_setprio(1); MFMAQ(1, 0); __builtin_amdgcn_s_setprio(0); BAR8();
        // P3: quadrant (0,1); A reads sealed by P2-end barrier
        LDB8(t, 1);
        if (t + 2 < NT) STAGE8(0, t + 2, 0);          // Alo(t+2)
        BAR8(); __builtin_amdgcn_s_setprio(1); MFMAQ(0, 1); __builtin_amdgcn_s_setprio(0); BAR8();
        // P4: quadrant (1,1); B reads sealed by P3-end barrier
        if (t + 2 < NT) { STAGE8(0, t + 2, 1);        // Ahi(t+2)
                          STAGE8(1, t + 2, 0); }      // Blo(t+2)  [moved from P2: r4 race fix]
        BAR8(); __builtin_amdgcn_s_setprio(1); MFMAQ(1, 1); __builtin_amdgcn_s_setprio(0);
        if (t + 2 < NT)      { VMC(6); }              // retire Bhi(t+1): tile t+1 landed
        else if (t + 1 < NT) { VMC(0); }              // drain before last tile
        if (t + 1 < NT) BAR8();
    }

    // ---- epilogue: D row=(lane>>4)*4+reg, col=lane&15 (m89-verified)
    const int rb = row0 + wm * 128 + lg * 4;
    const int cb = col0 + wn * 64 + l15;
#pragma unroll
    for (int mf = 0; mf < 8; ++mf) {
#pragma unroll
        for (int nf = 0; nf < 4; ++nf) {
            const int c = cb + nf * 16;
            const float bv = bias[c];
            const long base = (long)(rb + mf * 16) * N + c;
#pragma unroll
            for (int r = 0; r < 4; ++r) {
                const float v = acc[mf][nf][r] + bv;
                if (OUT_BF16) ((ushort*)Cout)[base + (long)r * N] = f2b(v);
                else          ((float*)Cout)[base + (long)r * N]  = v;
            }
        }
    }
#undef STAGE8
#undef LDA8
#undef LDB8
#undef MFMAQ
#undef BAR8
#undef VMC
}

// ---------------------------------------------------------------------------
// K3 GEMM (unchanged, known-good): 128x128 tile, BK=32, 4 waves.
// ---------------------------------------------------------------------------
template<bool OUT_BF16>
__global__ __launch_bounds__(256) void mfma_gemm_nt(
    const ushort* __restrict__ A, const ushort* __restrict__ B,
    const float* __restrict__ bias, void* __restrict__ Cout,
    int M, int N, int K, long sA, long sB, long sC)
{
    A += (long)blockIdx.z * sA;
    B += (long)blockIdx.z * sB;

    __shared__ __align__(16) ushort As[128 * 32];
    __shared__ __align__(16) ushort Bs[128 * 32];

    const int tid  = threadIdx.x;
    const int lane = tid & 63;
    const int wave = tid >> 6;
    const int wr   = (wave >> 1) * 64;
    const int wc   = (wave & 1) * 64;
    const int row0 = blockIdx.y * 128;
    const int col0 = blockIdx.x * 128;

    const int sr = tid >> 2;
    const int sc = (tid & 3) * 8;
    const ushort* gA0 = A + (long)(row0 + sr) * K + sc;
    const ushort* gA1 = A + (long)(row0 + sr + 64) * K + sc;
    const ushort* gB0 = B + (long)(col0 + sr) * K + sc;
    const ushort* gB1 = B + (long)(col0 + sr + 64) * K + sc;

    char* lA = (char*)As + wave * 1024;
    char* lB = (char*)Bs + wave * 1024;

    const int fr = lane & 15;
    const int kg = (lane >> 4) * 8;

    f32x4 acc[4][4] = {};

    for (int k0 = 0; k0 < K; k0 += 32) {
        if (k0) __syncthreads();
        GLL(gA0 + k0, lA);
        GLL(gA1 + k0, lA + 4096);
        GLL(gB0 + k0, lB);
        GLL(gB1 + k0, lB + 4096);
        __syncthreads();

        short8 a[4], b[4];
        #pragma unroll
        for (int m = 0; m < 4; ++m)
            a[m] = *(const short8*)(As + (wr + m * 16 + fr) * 32 + kg);
        #pragma unroll
        for (int n = 0; n < 4; ++n)
            b[n] = *(const short8*)(Bs + (wc + n * 16 + fr) * 32 + kg);

        #pragma unroll
        for (int m = 0; m < 4; ++m)
            #pragma unroll
            for (int n = 0; n < 4; ++n)
                acc[m][n] = __builtin_amdgcn_mfma_f32_16x16x32_bf16(
                    a[m], b[n], acc[m][n], 0, 0, 0);
    }

    const int rbase = row0 + wr + (lane >> 4) * 4;
    const int cbase = col0 + wc + (lane & 15);
    const long zoff = (long)blockIdx.z * sC;
    #pragma unroll
    for (int m = 0; m < 4; ++m) {
        #pragma unroll
        for (int n = 0; n < 4; ++n) {
            const int c = cbase + n * 16;
            const float bv = bias[c];
            #pragma unroll
            for (int r = 0; r < 4; ++r) {
                const long off = zoff + (long)(rbase + m * 16 + r) * N + c;
                const float v = acc[m][n][r] + bv;
                if (OUT_BF16) ((ushort*)Cout)[off] = f2b(v);
                else          ((float*)Cout)[off]  = v;
            }
        }
    }
}

// ---------------------------------------------------------------------------
// K2a: partial sums over a 128-token chunk, stored TRANSPOSED (V-dim first):
//   Mtp[chunk][bh][dp][d] = (1/8) * sum_{n in chunk} V[n][dp] * K[n][d]
// (unchanged, known-good)
// ---------------------------------------------------------------------------
__global__ __launch_bounds__(256) void ktv_partial(
    const ushort* __restrict__ y, float* __restrict__ Mtp)
{
    const int chunk = blockIdx.x;
    const int bh    = blockIdx.y;
    const int b = bh >> 3, h = bh & 7;
    const ushort* Kp = y + (long)b * YB_STRIDE + QKV_SZ     + h * HDIM;
    const ushort* Vp = y + (long)b * YB_STRIDE + 2 * QKV_SZ + h * HDIM;

    __shared__ __align__(16) float Ks[64][68];
    __shared__ __align__(16) float Vs[64][68];

    const int tid = threadIdx.x;
    const int tx = tid & 15, ty = tid >> 4;
    const int lr = tid >> 2;
    const int ls = (tid & 3) * 16;

    float acc[4][4] = {};                  // [i -> d (K-dim)][j -> dp (V-dim)]

    for (int s = 0; s < 2; ++s) {
        const int n0 = chunk * 128 + s * 64;
        const ushort* kr = Kp + (long)(n0 + lr) * CH + ls;
        const ushort* vr = Vp + (long)(n0 + lr) * CH + ls;
        const uint4 k0 = *(const uint4*)kr;
        const uint4 k1 = *(const uint4*)(kr + 8);
        const uint4 v0 = *(const uint4*)vr;
        const uint4 v1 = *(const uint4*)(vr + 8);
        if (s) __syncthreads();
        unsigned int kw[8] = {k0.x,k0.y,k0.z,k0.w,k1.x,k1.y,k1.z,k1.w};
        unsigned int vw[8] = {v0.x,v0.y,v0.z,v0.w,v1.x,v1.y,v1.z,v1.w};
        #pragma unroll
        for (int t = 0; t < 8; ++t) {
            unp(kw[t], Ks[lr][ls + 2*t], Ks[lr][ls + 2*t + 1]);
            unp(vw[t], Vs[lr][ls + 2*t], Vs[lr][ls + 2*t + 1]);
        }
        __syncthreads();

        #pragma unroll 8
        for (int nn = 0; nn < 64; ++nn) {
            const float4 ka = *(const float4*)&Ks[nn][ty * 4];
            const float4 vb = *(const float4*)&Vs[nn][tx * 4];
            const float kk[4] = {ka.x, ka.y, ka.z, ka.w};
            const float vv[4] = {vb.x, vb.y, vb.z, vb.w};
            #pragma unroll
            for (int i = 0; i < 4; ++i)
                #pragma unroll
                for (int j = 0; j < 4; ++j)
                    acc[i][j] = fmaf(kk[i], vv[j], acc[i][j]);
        }
        __syncthreads();
    }

    float* Mo = Mtp + ((long)chunk * 32 + bh) * 4096;
    #pragma unroll
    for (int j = 0; j < 4; ++j) {
        float4 st;
        st.x = acc[0][j] * 0.125f; st.y = acc[1][j] * 0.125f;
        st.z = acc[2][j] * 0.125f; st.w = acc[3][j] * 0.125f;
        *(float4*)&Mo[(tx * 4 + j) * 64 + ty * 4] = st;
    }
}

// ---------------------------------------------------------------------------
// K2r: reduce chunk partials once: Msum[bh][e] = sum_c Mtp[c][bh][e]
// ---------------------------------------------------------------------------
__global__ __launch_bounds__(256) void reduce_mtp(
    const float* __restrict__ Mtp, float* __restrict__ Msum)
{
    const int bh = blockIdx.x;
    for (int e = threadIdx.x; e < 4096; e += 256) {
        float s = 0.f;
        #pragma unroll
        for (int c = 0; c < KVCHUNK; ++c)
            s += Mtp[((long)c * 32 + bh) * 4096 + e];
        Msum[(long)bh * 4096 + e] = s;
    }
}

// ---------------------------------------------------------------------------
// K2b: Pt[b][f][64h+q] = sum_e w_out[f][64h+e] * Ms[e][q]
// ---------------------------------------------------------------------------
__global__ __launch_bounds__(256) void fold_pt(
    const float* __restrict__ Msum, const float* __restrict__ w_out,
    ushort* __restrict__ Pt)
{
    const int fc = blockIdx.x;   // 0..7
    const int bh = blockIdx.y;   // 0..31
    const int b = bh >> 3, h = bh & 7;

    __shared__ __align__(16) float Ms[64][68];

    const int tid = threadIdx.x;
    const int tx = tid & 15, ty = tid >> 4;

    #pragma unroll
    for (int j = 0; j < 16; ++j) {
        const int e = j * 256 + tid;
        Ms[e >> 6][e & 63] = Msum[(long)bh * 4096 + e];
    }
    __syncthreads();

    const int fbase = fc * 64 + ty * 4;
    float acc[4][4] = {};
    for (int d = 0; d < 64; ++d) {
        const float4 mv = *(const float4*)&Ms[d][tx * 4];
        const float mm[4] = {mv.x, mv.y, mv.z, mv.w};
        #pragma unroll
        for (int i = 0; i < 4; ++i) {
            const float w = w_out[(long)(fbase + i) * CH + h * HDIM + d];
            #pragma unroll
            for (int j = 0; j < 4; ++j)
                acc[i][j] = fmaf(w, mm[j], acc[i][j]);
        }
    }
    #pragma unroll
    for (int i = 0; i < 4; ++i) {
        ushort4 o;
        o.x = f2b(acc[i][0]); o.y = f2b(acc[i][1]);
        o.z = f2b(acc[i][2]); o.w = f2b(acc[i][3]);
        *(ushort4*)&Pt[(((long)b * CH) + fbase + i) * CH + h * HDIM + tx * 4] = o;
    }
}

// ---------------------------------------------------------------------------
extern "C" void kernel_launch(void* const* d_in, const int* in_sizes, int n_in,
                              void* d_out, int out_size, void* d_ws, size_t ws_size,
                              hipStream_t stream)
{
    const float* x     = (const float*)d_in[0];   // [4,2304,512]
    const float* w_in  = (const float*)d_in[1];   // [1536,512]
    const float* b_in  = (const float*)d_in[2];   // [1536]
    const float* w_out = (const float*)d_in[3];   // [512,512]
    const float* b_out = (const float*)d_in[4];   // [512]
    float* out = (float*)d_out;                   // [4,2304,512] fp32

    char* ws = (char*)d_ws;
    ushort* xb   = (ushort*)ws;                      //  9,437,184 B
    ushort* wb   = (ushort*)(ws + 9437184);          //  1,572,864 B (contig after xb)
    ushort* y    = (ushort*)(ws + 11010048);         // 28,311,552 B bf16 [4][2304][1536]
    float*  Mtp  = (float*) (ws + 39321600);         //  9,437,184 B
    float*  Msum = (float*) (ws + 48758784);         //    524,288 B
    ushort* Pt   = (ushort*)(ws + 49283072);         //  2,097,152 B -> 51.4 MB total

    // K0: converts (one launch; wb contiguous after xb)
    cvt_bf16_2<<<5376, 256, 0, stream>>>(x, w_in, xb, 1179648, 196608);

    // K1: y = x @ w_in^T + b_in  (bf16 out), 256^2 8-phase. M=9216 N=1536 K=512
    gemm256_8ph<512, true><<<dim3(F3 / 256, (BATCH * TOK) / 256), 512, 0, stream>>>(
        xb, wb, b_in, y, F3);

    // K2a: chunk-partial (V^T K)/8
    ktv_partial<<<dim3(KVCHUNK, BATCH * NHEAD), 256, 0, stream>>>(y, Mtp);

    // K2r: reduce chunks once
    reduce_mtp<<<dim3(BATCH * NHEAD), 256, 0, stream>>>(Mtp, Msum);

    // K2b: fold w_out -> Pt bf16
    fold_pt<<<dim3(8, BATCH * NHEAD), 256, 0, stream>>>(Msum, w_out, Pt);

    // K3: out[b] = Q[b] @ Pt[b]^T + b_out (fp32 out), M=2304 N=512 K=512, z=4
    mfma_gemm_nt<false><<<dim3(CH / 128, TOK / 128, BATCH), 256, 0, stream>>>(
        y, Pt, b_out, out, TOK, CH, CH, YB_STRIDE, (long)CH * CH, QKV_SZ);
}

// Round 6
// 77.286 us; speedup vs baseline: 8.1107x; 1.0084x over previous
//
#include <hip/hip_runtime.h>
#include <hip/hip_bf16.h>

#define BATCH 4
#define TOK   2304
#define CH    512
#define NHEAD 8
#define HDIM  64
#define F3    1536
#define YB_STRIDE ((long)TOK * F3)   // y per-batch stride (elements)
#define QKV_SZ    ((long)TOK * CH)   // one Q/K/V third (elements)
#define KVCHUNK   18                 // token chunks for K^T V partials (2304/18=128)

typedef __attribute__((ext_vector_type(8))) short short8;   // 8 bf16 = 4 VGPRs
typedef __attribute__((ext_vector_type(4))) float f32x4;

__device__ inline ushort f2b(float f) {
    __hip_bfloat16 h = __float2bfloat16(f);
    return *reinterpret_cast<ushort*>(&h);
}
__device__ inline void unp(unsigned int u, float& lo, float& hi) {
    union { unsigned int i; float f; } a, c;
    a.i = u << 16; c.i = u & 0xffff0000u;
    lo = a.f; hi = c.f;
}

// global -> LDS direct copy, 16B per lane; lds dest = wave-uniform base + lane*16
#define GLL(gp, lp) __builtin_amdgcn_global_load_lds( \
    (const __attribute__((address_space(1))) unsigned int*)(gp), \
    (__attribute__((address_space(3))) unsigned int*)(lp), 16, 0, 0)

// ---------------------------------------------------------------------------
// K0: fp32 -> bf16 convert for x and w_in in one launch (wb contiguous after xb)
// ---------------------------------------------------------------------------
__global__ __launch_bounds__(256) void cvt_bf16_2(
    const float* __restrict__ x, const float* __restrict__ w,
    ushort* __restrict__ xb_wb, int nx4, int nw4)
{
    const int i = blockIdx.x * 256 + threadIdx.x;
    float4 v;
    if (i < nx4)                v = ((const float4*)x)[i];
    else if (i < nx4 + nw4)     v = ((const float4*)w)[i - nx4];
    else return;
    ushort4 o;
    o.x = f2b(v.x); o.y = f2b(v.y); o.z = f2b(v.z); o.w = f2b(v.w);
    ((ushort4*)xb_wb)[i] = o;
}

// ---------------------------------------------------------------------------
// K1: 256x256-tile, BK=64, 8-wave (2Mx4N), 8-phase counted-vmcnt MFMA GEMM NT.
// (structure verified passing round 5; this round adds only the XCD swizzle)
// READ-SEAL schedule: P1:Bhi(t+1)[other buf]  P3:Alo(t+2)  P4:Ahi(t+2),Blo(t+2)
// Ledger: end-of-t VMC(6) leaves {Alo,Ahi,Blo}(t+2) in flight; t=NT-2: VMC(0).
// ---------------------------------------------------------------------------
template<int KDIM, bool OUT_BF16>
__global__ __launch_bounds__(512, 2) void gemm256_8ph(
    const ushort* __restrict__ A, const ushort* __restrict__ B,
    const float* __restrict__ bias, void* __restrict__ Cout, int N)
{
    constexpr int NT = KDIM / 64;
    __shared__ __align__(16) char smem[131072];

    const int tid  = threadIdx.x;
    const int lane = tid & 63, wave = tid >> 6;
    const int wm = wave >> 2, wn = wave & 3;           // 2 x 4 wave grid

    // T1 XCD swizzle (nwg % 8 == 0 by construction: 216 blocks)
    const int nbx  = gridDim.x;
    const int flat = blockIdx.x + nbx * blockIdx.y;
    const int cpx  = (nbx * gridDim.y) >> 3;
    const int swz  = (flat & 7) * cpx + (flat >> 3);
    const int row0 = (swz / nbx) * 256, col0 = (swz % nbx) * 256;

    // staging invariants: thread covers LDS linear (srow, (tid&7)*16B) per chunk
    const int srow = tid >> 3;                          // 0..63 within chunk
    const int scol = ((tid & 7) ^ (srow & 7)) << 3;     // inverse-swizzled src col (elems)
    const ushort* gA = A + (long)(row0 + srow) * KDIM + scol;
    const ushort* gB = B + (long)(col0 + srow) * KDIM + scol;
    char* ldsW = smem + wave * 1024;                    // + op*65536 + buf*32768 + half*16384 + chunk*8192

    // fragment-read invariants
    const int l15 = lane & 15, lg = lane >> 4, l7 = lane & 7;
    const int cp[2] = { (lg * 16) ^ (l7 * 16), (64 + lg * 16) ^ (l7 * 16) };
    const char* rdA = smem + (wm * 128 + l15) * 128;
    const char* rdB = smem + 65536 + (wn * 64 + l15) * 128;

    f32x4  acc[8][4] = {};
    short8 a[2][4][2], b[2][2];

#define STAGE8(op, t, h) do { \
    const ushort* _g = ((op) ? gB : gA) + ((h) * 128) * KDIM + (t) * 64; \
    char* _l = ldsW + (op) * 65536 + ((t) & 1) * 32768 + (h) * 16384; \
    GLL(_g, _l); \
    GLL(_g + 64 * KDIM, _l + 8192); \
} while (0)

#define LDA8(t, mh) do { \
    const char* _p = rdA + ((t) & 1) * 32768 + (mh) * 8192; \
    _Pragma("unroll") for (int mf = 0; mf < 4; ++mf) { \
        a[mh][mf][0] = *(const short8*)(_p + mf * 2048 + cp[0]); \
        a[mh][mf][1] = *(const short8*)(_p + mf * 2048 + cp[1]); } \
} while (0)

#define LDB8(t, nh) do { \
    const char* _p = rdB + ((t) & 1) * 32768 + (nh) * 4096; \
    _Pragma("unroll") for (int j = 0; j < 2; ++j) { \
        b[j][0] = *(const short8*)(_p + j * 2048 + cp[0]); \
        b[j][1] = *(const short8*)(_p + j * 2048 + cp[1]); } \
} while (0)

#define MFMAQ(mh, nh) do { \
    _Pragma("unroll") for (int mf = 0; mf < 4; ++mf) \
    _Pragma("unroll") for (int j = 0; j < 2; ++j) \
    _Pragma("unroll") for (int ks = 0; ks < 2; ++ks) \
        acc[(mh)*4+mf][(nh)*2+j] = __builtin_amdgcn_mfma_f32_16x16x32_bf16( \
            a[mh][mf][ks], b[j][ks], acc[(mh)*4+mf][(nh)*2+j], 0, 0, 0); \
} while (0)

#define BAR8() __builtin_amdgcn_s_barrier()
#define VMC(n) asm volatile("s_waitcnt vmcnt(" #n ")" ::: "memory")

    // ---- prologue: tile0 (4 half-tiles) + tile1 {Blo, Alo, Ahi}
    STAGE8(0, 0, 0); STAGE8(0, 0, 1); STAGE8(1, 0, 0); STAGE8(1, 0, 1);
    VMC(4);
    STAGE8(1, 1, 0); STAGE8(0, 1, 0); STAGE8(0, 1, 1);
    VMC(6);                               // 14 issued, retire oldest 8 = all tile0
    BAR8();

#pragma unroll
    for (int t = 0; t < NT; ++t) {
        // P1: quadrant (0,0)
        LDA8(t, 0); LDB8(t, 0);
        if (t + 1 < NT) STAGE8(1, t + 1, 1);          // Bhi(t+1) -> other buf (always safe)
        BAR8(); __builtin_amdgcn_s_setprio(1); MFMAQ(0, 0); __builtin_amdgcn_s_setprio(0); BAR8();
        // P2: quadrant (1,0) — no staging (no region is sealed yet)
        LDA8(t, 1);
        BAR8(); __builtin_amdgcn_s_setprio(1); MFMAQ(1, 0); __builtin_amdgcn_s_setprio(0); BAR8();
        // P3: quadrant (0,1); A reads sealed by P2-end barrier
        LDB8(t, 1);
        if (t + 2 < NT) STAGE8(0, t + 2, 0);          // Alo(t+2)
        BAR8(); __builtin_amdgcn_s_setprio(1); MFMAQ(0, 1); __builtin_amdgcn_s_setprio(0); BAR8();
        // P4: quadrant (1,1); B reads sealed by P3-end barrier
        if (t + 2 < NT) { STAGE8(0, t + 2, 1);        // Ahi(t+2)
                          STAGE8(1, t + 2, 0); }      // Blo(t+2)
        BAR8(); __builtin_amdgcn_s_setprio(1); MFMAQ(1, 1); __builtin_amdgcn_s_setprio(0);
        if (t + 2 < NT)      { VMC(6); }              // retire Bhi(t+1): tile t+1 landed
        else if (t + 1 < NT) { VMC(0); }              // drain before last tile
        if (t + 1 < NT) BAR8();
    }

    // ---- epilogue: D row=(lane>>4)*4+reg, col=lane&15 (m89-verified)
    const int rb = row0 + wm * 128 + lg * 4;
    const int cb = col0 + wn * 64 + l15;
#pragma unroll
    for (int mf = 0; mf < 8; ++mf) {
#pragma unroll
        for (int nf = 0; nf < 4; ++nf) {
            const int c = cb + nf * 16;
            const float bv = bias[c];
            const long base = (long)(rb + mf * 16) * N + c;
#pragma unroll
            for (int r = 0; r < 4; ++r) {
                const float v = acc[mf][nf][r] + bv;
                if (OUT_BF16) ((ushort*)Cout)[base + (long)r * N] = f2b(v);
                else          ((float*)Cout)[base + (long)r * N]  = v;
            }
        }
    }
#undef STAGE8
#undef LDA8
#undef LDB8
#undef MFMAQ
#undef BAR8
#undef VMC
}

// ---------------------------------------------------------------------------
// K3 GEMM (known-good m97 structure + T1 XCD swizzle): 128x128, BK=32, 4 waves.
// Requires gridDim.x*y*z % 8 == 0 (288 here).
// ---------------------------------------------------------------------------
template<bool OUT_BF16>
__global__ __launch_bounds__(256) void mfma_gemm_nt(
    const ushort* __restrict__ A, const ushort* __restrict__ B,
    const float* __restrict__ bias, void* __restrict__ Cout,
    int M, int N, int K, long sA, long sB, long sC)
{
    // T1 XCD swizzle over the flattened 3D grid
    const int gx = gridDim.x, gxy = gridDim.x * gridDim.y;
    const int flat = blockIdx.x + gx * blockIdx.y + gxy * blockIdx.z;
    const int cpx  = (gxy * gridDim.z) >> 3;
    const int swz  = (flat & 7) * cpx + (flat >> 3);
    const int bz = swz / gxy, rem = swz % gxy;
    const int row0 = (rem / gx) * 128, col0 = (rem % gx) * 128;

    A += (long)bz * sA;
    B += (long)bz * sB;

    __shared__ __align__(16) ushort As[128 * 32];
    __shared__ __align__(16) ushort Bs[128 * 32];

    const int tid  = threadIdx.x;
    const int lane = tid & 63;
    const int wave = tid >> 6;
    const int wr   = (wave >> 1) * 64;
    const int wc   = (wave & 1) * 64;

    const int sr = tid >> 2;
    const int sc = (tid & 3) * 8;
    const ushort* gA0 = A + (long)(row0 + sr) * K + sc;
    const ushort* gA1 = A + (long)(row0 + sr + 64) * K + sc;
    const ushort* gB0 = B + (long)(col0 + sr) * K + sc;
    const ushort* gB1 = B + (long)(col0 + sr + 64) * K + sc;

    char* lA = (char*)As + wave * 1024;
    char* lB = (char*)Bs + wave * 1024;

    const int fr = lane & 15;
    const int kg = (lane >> 4) * 8;

    f32x4 acc[4][4] = {};

    for (int k0 = 0; k0 < K; k0 += 32) {
        if (k0) __syncthreads();
        GLL(gA0 + k0, lA);
        GLL(gA1 + k0, lA + 4096);
        GLL(gB0 + k0, lB);
        GLL(gB1 + k0, lB + 4096);
        __syncthreads();

        short8 a[4], b[4];
        #pragma unroll
        for (int m = 0; m < 4; ++m)
            a[m] = *(const short8*)(As + (wr + m * 16 + fr) * 32 + kg);
        #pragma unroll
        for (int n = 0; n < 4; ++n)
            b[n] = *(const short8*)(Bs + (wc + n * 16 + fr) * 32 + kg);

        #pragma unroll
        for (int m = 0; m < 4; ++m)
            #pragma unroll
            for (int n = 0; n < 4; ++n)
                acc[m][n] = __builtin_amdgcn_mfma_f32_16x16x32_bf16(
                    a[m], b[n], acc[m][n], 0, 0, 0);
    }

    const int rbase = row0 + wr + (lane >> 4) * 4;
    const int cbase = col0 + wc + (lane & 15);
    const long zoff = (long)bz * sC;
    #pragma unroll
    for (int m = 0; m < 4; ++m) {
        #pragma unroll
        for (int n = 0; n < 4; ++n) {
            const int c = cbase + n * 16;
            const float bv = bias[c];
            #pragma unroll
            for (int r = 0; r < 4; ++r) {
                const long off = zoff + (long)(rbase + m * 16 + r) * N + c;
                const float v = acc[m][n][r] + bv;
                if (OUT_BF16) ((ushort*)Cout)[off] = f2b(v);
                else          ((float*)Cout)[off]  = v;
            }
        }
    }
}

// ---------------------------------------------------------------------------
// K2a: partial sums over a 128-token chunk, stored TRANSPOSED (V-dim first):
//   Mtp[chunk][bh][dp][d] = (1/8) * sum_{n in chunk} V[n][dp] * K[n][d]
// (round-5 verified; staging writes now packed as ds_write_b128)
// ---------------------------------------------------------------------------
__global__ __launch_bounds__(256) void ktv_partial(
    const ushort* __restrict__ y, float* __restrict__ Mtp)
{
    const int chunk = blockIdx.x;
    const int bh    = blockIdx.y;
    const int b = bh >> 3, h = bh & 7;
    const ushort* Kp = y + (long)b * YB_STRIDE + QKV_SZ     + h * HDIM;
    const ushort* Vp = y + (long)b * YB_STRIDE + 2 * QKV_SZ + h * HDIM;

    __shared__ __align__(16) float Ks[64][68];
    __shared__ __align__(16) float Vs[64][68];

    const int tid = threadIdx.x;
    const int tx = tid & 15, ty = tid >> 4;
    const int lr = tid >> 2;
    const int ls = (tid & 3) * 16;

    float acc[4][4] = {};                  // [i -> d (K-dim)][j -> dp (V-dim)]

    for (int s = 0; s < 2; ++s) {
        const int n0 = chunk * 128 + s * 64;
        const ushort* kr = Kp + (long)(n0 + lr) * CH + ls;
        const ushort* vr = Vp + (long)(n0 + lr) * CH + ls;
        const uint4 k0 = *(const uint4*)kr;
        const uint4 k1 = *(const uint4*)(kr + 8);
        const uint4 v0 = *(const uint4*)vr;
        const uint4 v1 = *(const uint4*)(vr + 8);
        if (s) __syncthreads();
        unsigned int kw[8] = {k0.x,k0.y,k0.z,k0.w,k1.x,k1.y,k1.z,k1.w};
        unsigned int vw[8] = {v0.x,v0.y,v0.z,v0.w,v1.x,v1.y,v1.z,v1.w};
        #pragma unroll
        for (int u = 0; u < 4; ++u) {      // packed: 8 x ds_write_b128 (was 32 b32)
            float4 kf, vf;
            unp(kw[2*u],   kf.x, kf.y); unp(kw[2*u+1], kf.z, kf.w);
            unp(vw[2*u],   vf.x, vf.y); unp(vw[2*u+1], vf.z, vf.w);
            *(float4*)&Ks[lr][ls + 4*u] = kf;
            *(float4*)&Vs[lr][ls + 4*u] = vf;
        }
        __syncthreads();

        #pragma unroll 8
        for (int nn = 0; nn < 64; ++nn) {
            const float4 ka = *(const float4*)&Ks[nn][ty * 4];
            const float4 vb = *(const float4*)&Vs[nn][tx * 4];
            const float kk[4] = {ka.x, ka.y, ka.z, ka.w};
            const float vv[4] = {vb.x, vb.y, vb.z, vb.w};
            #pragma unroll
            for (int i = 0; i < 4; ++i)
                #pragma unroll
                for (int j = 0; j < 4; ++j)
                    acc[i][j] = fmaf(kk[i], vv[j], acc[i][j]);
        }
        __syncthreads();
    }

    float* Mo = Mtp + ((long)chunk * 32 + bh) * 4096;
    #pragma unroll
    for (int j = 0; j < 4; ++j) {
        float4 st;
        st.x = acc[0][j] * 0.125f; st.y = acc[1][j] * 0.125f;
        st.z = acc[2][j] * 0.125f; st.w = acc[3][j] * 0.125f;
        *(float4*)&Mo[(tx * 4 + j) * 64 + ty * 4] = st;
    }
}

// ---------------------------------------------------------------------------
// K2b: Pt[b][f][64h+q] = sum_e w_out[f][64h+e] * Ms[e][q]
// Chunk reduction inlined (round-3-verified pattern); Mtp re-reads are L2-hits.
// ---------------------------------------------------------------------------
__global__ __launch_bounds__(256) void fold_pt(
    const float* __restrict__ Mtp, const float* __restrict__ w_out,
    ushort* __restrict__ Pt)
{
    const int fc = blockIdx.x;   // 0..7
    const int bh = blockIdx.y;   // 0..31
    const int b = bh >> 3, h = bh & 7;

    __shared__ __align__(16) float Ms[64][68];

    const int tid = threadIdx.x;
    const int tx = tid & 15, ty = tid >> 4;

    #pragma unroll
    for (int j = 0; j < 16; ++j) {
        const int e = j * 256 + tid;       // 0..4095
        float sum = 0.f;
        #pragma unroll
        for (int c = 0; c < KVCHUNK; ++c)
            sum += Mtp[((long)c * 32 + bh) * 4096 + e];
        Ms[e >> 6][e & 63] = sum;
    }
    __syncthreads();

    const int fbase = fc * 64 + ty * 4;
    float acc[4][4] = {};
    for (int d = 0; d < 64; ++d) {
        const float4 mv = *(const float4*)&Ms[d][tx * 4];
        const float mm[4] = {mv.x, mv.y, mv.z, mv.w};
        #pragma unroll
        for (int i = 0; i < 4; ++i) {
            const float w = w_out[(long)(fbase + i) * CH + h * HDIM + d];
            #pragma unroll
            for (int j = 0; j < 4; ++j)
                acc[i][j] = fmaf(w, mm[j], acc[i][j]);
        }
    }
    #pragma unroll
    for (int i = 0; i < 4; ++i) {
        ushort4 o;
        o.x = f2b(acc[i][0]); o.y = f2b(acc[i][1]);
        o.z = f2b(acc[i][2]); o.w = f2b(acc[i][3]);
        *(ushort4*)&Pt[(((long)b * CH) + fbase + i) * CH + h * HDIM + tx * 4] = o;
    }
}

// ---------------------------------------------------------------------------
extern "C" void kernel_launch(void* const* d_in, const int* in_sizes, int n_in,
                              void* d_out, int out_size, void* d_ws, size_t ws_size,
                              hipStream_t stream)
{
    const float* x     = (const float*)d_in[0];   // [4,2304,512]
    const float* w_in  = (const float*)d_in[1];   // [1536,512]
    const float* b_in  = (const float*)d_in[2];   // [1536]
    const float* w_out = (const float*)d_in[3];   // [512,512]
    const float* b_out = (const float*)d_in[4];   // [512]
    float* out = (float*)d_out;                   // [4,2304,512] fp32

    char* ws = (char*)d_ws;
    ushort* xb   = (ushort*)ws;                      //  9,437,184 B
    ushort* wb   = (ushort*)(ws + 9437184);          //  1,572,864 B (contig after xb)
    ushort* y    = (ushort*)(ws + 11010048);         // 28,311,552 B bf16 [4][2304][1536]
    float*  Mtp  = (float*) (ws + 39321600);         //  9,437,184 B
    ushort* Pt   = (ushort*)(ws + 48758784);         //  2,097,152 B -> 50.9 MB total

    // K0: converts (one launch; wb contiguous after xb)
    cvt_bf16_2<<<5376, 256, 0, stream>>>(x, w_in, xb, 1179648, 196608);

    // K1: y = x @ w_in^T + b_in  (bf16 out), 256^2 8-phase. M=9216 N=1536 K=512
    gemm256_8ph<512, true><<<dim3(F3 / 256, (BATCH * TOK) / 256), 512, 0, stream>>>(
        xb, wb, b_in, y, F3);

    // K2a: chunk-partial (V^T K)/8
    ktv_partial<<<dim3(KVCHUNK, BATCH * NHEAD), 256, 0, stream>>>(y, Mtp);

    // K2b: reduce chunks inline + fold w_out -> Pt bf16
    fold_pt<<<dim3(8, BATCH * NHEAD), 256, 0, stream>>>(Mtp, w_out, Pt);

    // K3: out[b] = Q[b] @ Pt[b]^T + b_out (fp32 out), M=2304 N=512 K=512, z=4
    mfma_gemm_nt<false><<<dim3(CH / 128, TOK / 128, BATCH), 256, 0, stream>>>(
        y, Pt, b_out, out, TOK, CH, CH, YB_STRIDE, (long)CH * CH, QKV_SZ);
}